// Round 3
// baseline (8304.028 us; speedup 1.0000x reference)
//
#include <hip/hip_runtime.h>

// BI-LSTM (TF LSTMCell w/ projection), T=160 B=640 F=40 HID=768 PROJ=256, 3 layers x 2 dirs.
// R3: gate kernel rebuilt around MFMA economics:
//  - 128x128 tile, 4 waves of 64x64 (4x4 acc of 16x16x32) -> 2x fewer LDS reads per MFMA
//  - global_load_lds width=16 staging into FRAGMENT-ORDER microtiles (16x32 = 1KB in exact
//    MFMA lane order): satisfies the wave-uniform-base DMA constraint without padding,
//    makes frag ds_read_b128 conflict-free at addr = lane*16 + const, kills ds_write traffic.
//  - epilogue reuses LDS as zs[128][65] f32 in two 64-col passes (32 hidden units per block).
// Pipeline structure unchanged from R2 (layer-wavefront, 6 z-slices per launch).

typedef _Float16 h8 __attribute__((ext_vector_type(8)));
typedef float f4 __attribute__((ext_vector_type(4)));

#define T_STEPS 160
#define NB 640
#define HID 768
#define PROJ 256
#define NGATE 3072           // 4*HID

__device__ __forceinline__ float sigm(float x) { return 1.0f / (1.0f + __expf(-x)); }
__device__ __forceinline__ float tanh_fast(float x) { return 2.0f / (1.0f + __expf(-2.0f * x)) - 1.0f; }

typedef __attribute__((address_space(1))) const void gas_t;
typedef __attribute__((address_space(3))) void las_t;
__device__ __forceinline__ void dma16(void* lds, const void* g) {
  // async global->LDS DMA, 16B/lane; LDS dest = wave-uniform base + lane*16 (HW-added)
  __builtin_amdgcn_global_load_lds((gas_t*)g, (las_t*)lds, 16, 0, 0);
}

struct GateArgs {
  const _Float16* A0[6];   // x-part source (X16 for l=0, prev-layer ring slot otherwise)
  const _Float16* A1[6];   // own h ring slot (h_{t-1} fw / h_{t+1} bw)
  const _Float16* Bw[6];   // WkT, gate-interleaved [3072][Kpad]
  const float*    bias[6];
  float*          cst[6];
  _Float16*       g[6];
  int w0[6];
  int lda0[6];
  int K[6];
  int act[6];
};

struct ProjArgs {
  const _Float16* G[6];    // [640][768] fp16
  const _Float16* Wp[6];   // [256][768] fp16 (B^T)
  _Float16* out[6];        // own ring write slot
  _Float16* out2[6];       // optional embed capture (layer 2, t in {0,159})
  int act[6];
};

// ---------------- gate GEMM: z = [x,h] @ WkT^T, fused bias+gates+c-update -> g ----------------
__global__ __launch_bounds__(256) void gate_step(GateArgs args) {
  const int z = blockIdx.z;
  if (!args.act[z]) return;

  __shared__ __align__(16) char sm[33280];   // A 16KB | B 16KB, overlaid by zs[128][65] f32
  char* smA = sm;
  char* smB = sm + 16384;
  float (*zs)[65] = (float(*)[65])sm;

  const _Float16* A0 = args.A0[z];
  const _Float16* A1 = args.A1[z];
  const _Float16* Bw = args.Bw[z];
  const int w0 = args.w0[z], lda0 = args.lda0[z], K = args.K[z];
  const int n0 = blockIdx.x * 128;
  const int m0 = blockIdx.y * 128;
  const int tid = threadIdx.x;
  const int lane = tid & 63;
  const int wv = tid >> 6;
  const int wm = (wv & 1) * 64;    // wave's 64x64 quadrant
  const int wn = (wv >> 1) * 64;

  f4 acc[4][4] = {};

  // staging lane roles: row-in-microtile = lane&15, k-colgroup = (lane>>4)*8 halves
  const int mrow = lane & 15;
  const int kcol = (lane >> 4) * 8;

  for (int k0 = 0; k0 < K; k0 += 64) {
    __syncthreads();                        // prior iter's frag reads complete
    const _Float16* Asrc; int Alda, kof;    // w0 is a multiple of 64 -> uniform per iter
    if (k0 < w0) { Asrc = A0; Alda = lda0; kof = k0; }
    else         { Asrc = A1; Alda = 256;  kof = k0 - w0; }
#pragma unroll
    for (int j = 0; j < 4; ++j) {
      int q = wv + 4 * j;                   // microtile id: mi = q>>1, kk = q&1
      int mi = q >> 1, kk = q & 1;
      dma16(smA + q * 1024,
            Asrc + (size_t)(m0 + mi * 16 + mrow) * Alda + kof + kk * 32 + kcol);
      dma16(smB + q * 1024,
            Bw + (size_t)(n0 + mi * 16 + mrow) * K + k0 + kk * 32 + kcol);
    }
    __syncthreads();                        // drains vmcnt (DMA complete) per barrier semantics
#pragma unroll
    for (int kk = 0; kk < 2; ++kk) {
      h8 af[4], bf[4];
#pragma unroll
      for (int i = 0; i < 4; ++i) {
        int miA = (wm >> 4) + i;            // wave's four 16-row groups
        int niB = (wn >> 4) + i;
        af[i] = *(const h8*)(smA + (miA * 2 + kk) * 1024 + lane * 16);
        bf[i] = *(const h8*)(smB + (niB * 2 + kk) * 1024 + lane * 16);
      }
#pragma unroll
      for (int i = 0; i < 4; ++i)
#pragma unroll
        for (int jn = 0; jn < 4; ++jn)
          acc[i][jn] = __builtin_amdgcn_mfma_f32_16x16x32_f16(af[i], bf[jn], acc[i][jn], 0, 0, 0);
    }
  }

  // epilogue: two 64-col passes through zs (16 units each)
  const float* bias = args.bias[z];
  float* cstate = args.cst[z];
  _Float16* gout = args.g[z];
#pragma unroll
  for (int p = 0; p < 2; ++p) {
    __syncthreads();
    if ((wv >> 1) == p) {                   // waves owning n-half p write their acc
#pragma unroll
      for (int mi = 0; mi < 4; ++mi)
#pragma unroll
        for (int ni = 0; ni < 4; ++ni)
#pragma unroll
          for (int r = 0; r < 4; ++r) {
            int row = wm + mi * 16 + ((lane >> 4) << 2) + r;  // C/D: row=(lane>>4)*4+reg
            int col = ni * 16 + (lane & 15);                  //      col=lane&15 (0..63)
            zs[row][col] = acc[mi][ni][r];
          }
    }
    __syncthreads();
    const int u0 = (n0 + p * 64) >> 2;      // first hidden unit of this pass
#pragma unroll
    for (int it = 0; it < 8; ++it) {
      int item = it * 256 + tid;            // 128 rows x 16 units
      int row = item >> 4;
      int u = item & 15;
      float zi = zs[row][4 * u + 0] + bias[0 * HID + u0 + u];
      float zj = zs[row][4 * u + 1] + bias[1 * HID + u0 + u];
      float zf = zs[row][4 * u + 2] + bias[2 * HID + u0 + u];
      float zo = zs[row][4 * u + 3] + bias[3 * HID + u0 + u];
      size_t co = (size_t)(m0 + row) * HID + u0 + u;
      float cold = cstate[co];
      float cnew = sigm(zf + 1.0f) * cold + sigm(zi) * tanh_fast(zj);  // forget_bias=1.0
      float g = sigm(zo) * tanh_fast(cnew);
      cstate[co] = cnew;
      gout[co] = (_Float16)g;
    }
  }
}

// ---------------- projection GEMM: h = g @ WpT^T ----------------
// 64x64 tile, 256 threads, K=768. (unchanged from R2)
__global__ __launch_bounds__(256) void proj_step(ProjArgs args) {
  const int z = blockIdx.z;
  if (!args.act[z]) return;

  __shared__ __align__(16) _Float16 As[64][72];
  __shared__ __align__(16) _Float16 Bs[64][72];

  const _Float16* A = args.G[z];
  const _Float16* B = args.Wp[z];
  const int n0 = blockIdx.x * 64;
  const int m0 = blockIdx.y * 64;
  const int tid = threadIdx.x;
  const int lane = tid & 63;
  const int wv = tid >> 6;
  const int wm = (wv & 1) * 32;
  const int wn = (wv >> 1) * 32;

  f4 acc[2][2] = {};
  const int lr = tid >> 3;
  const int lkg = (tid & 7) * 8;

  for (int k0 = 0; k0 < HID; k0 += 64) {
    const int gk = k0 + lkg;
    h8 av0 = *(const h8*)(A + (size_t)(m0 + lr) * HID + gk);
    h8 av1 = *(const h8*)(A + (size_t)(m0 + lr + 32) * HID + gk);
    h8 bv0 = *(const h8*)(B + (size_t)(n0 + lr) * HID + gk);
    h8 bv1 = *(const h8*)(B + (size_t)(n0 + lr + 32) * HID + gk);
    __syncthreads();
    *(h8*)&As[lr][lkg] = av0;
    *(h8*)&As[lr + 32][lkg] = av1;
    *(h8*)&Bs[lr][lkg] = bv0;
    *(h8*)&Bs[lr + 32][lkg] = bv1;
    __syncthreads();
    const int mr = wm + (lane & 15);
    const int nr = wn + (lane & 15);
#pragma unroll
    for (int kk = 0; kk < 2; ++kk) {
      const int kq = ((lane >> 4) * 8) + kk * 32;
      h8 a0 = *(const h8*)&As[mr][kq];
      h8 a1 = *(const h8*)&As[mr + 16][kq];
      h8 b0 = *(const h8*)&Bs[nr][kq];
      h8 b1 = *(const h8*)&Bs[nr + 16][kq];
      acc[0][0] = __builtin_amdgcn_mfma_f32_16x16x32_f16(a0, b0, acc[0][0], 0, 0, 0);
      acc[0][1] = __builtin_amdgcn_mfma_f32_16x16x32_f16(a0, b1, acc[0][1], 0, 0, 0);
      acc[1][0] = __builtin_amdgcn_mfma_f32_16x16x32_f16(a1, b0, acc[1][0], 0, 0, 0);
      acc[1][1] = __builtin_amdgcn_mfma_f32_16x16x32_f16(a1, b1, acc[1][1], 0, 0, 0);
    }
  }

  _Float16* outp = args.out[z];
  _Float16* out2 = args.out2[z];
#pragma unroll
  for (int mi = 0; mi < 2; ++mi)
#pragma unroll
    for (int ni = 0; ni < 2; ++ni)
#pragma unroll
      for (int r = 0; r < 4; ++r) {
        int row = wm + mi * 16 + ((lane >> 4) << 2) + r;
        int col = wn + ni * 16 + (lane & 15);
        _Float16 v = (_Float16)acc[mi][ni][r];
        size_t o = (size_t)(m0 + row) * PROJ + (n0 + col);
        outp[o] = v;
        if (out2) out2[o] = v;
      }
}

// ---------------- prep kernels ----------------
__global__ void convX(const float* __restrict__ X, _Float16* __restrict__ X16, size_t total) {
  size_t i = (size_t)blockIdx.x * 256 + threadIdx.x;
  if (i >= total) return;
  int p = (int)(i & 63);
  size_t tb = i >> 6;
  float v = (p < 40) ? X[tb * 40 + p] : 0.0f;
  X16[i] = (_Float16)v;
}

// Wk fp32 [Kin+256, 3072] -> WkT fp16 [3072][Kpad], gate-interleaved rows n'=4u+g,
// layer0 k-map: k<40 -> Wk[k]; 40..63 -> 0; 64..319 -> Wk[k-24]
__global__ void conv_wk(const float* __restrict__ Wk, _Float16* __restrict__ out,
                        int mode, int Kpad, size_t total) {
  size_t i = (size_t)blockIdx.x * 256 + threadIdx.x;
  if (i >= total) return;
  int k = (int)(i % Kpad);
  int n = (int)(i / Kpad);
  int u = n >> 2, g = n & 3;
  int col = g * HID + u;
  float v;
  if (mode == 0) {
    if (k < 40)      v = Wk[(size_t)k * NGATE + col];
    else if (k < 64) v = 0.0f;
    else             v = Wk[(size_t)(k - 24) * NGATE + col];
  } else {
    v = Wk[(size_t)k * NGATE + col];
  }
  out[i] = (_Float16)v;
}

__global__ void conv_wp(const float* __restrict__ Wp, _Float16* __restrict__ out, size_t total) {
  size_t i = (size_t)blockIdx.x * 256 + threadIdx.x;
  if (i >= total) return;
  int k = (int)(i % HID);
  int c = (int)(i / HID);
  out[i] = (_Float16)Wp[(size_t)k * PROJ + c];
}

// ---------------- readout ----------------
__global__ __launch_bounds__(256) void readout(const _Float16* __restrict__ E, float* __restrict__ out) {
  const size_t SL = (size_t)NB * PROJ;
  int b = blockIdx.x, tid = threadIdx.x;
  float v[2];
  float ss = 0.0f;
#pragma unroll
  for (int i = 0; i < 2; ++i) {
    int j = tid + i * 256;
    int d = j >> 8, c = j & 255;
    const _Float16* base = E + (size_t)d * 2 * SL;
    float a = (float)base[(size_t)b * PROJ + c];
    float zv = (float)base[SL + (size_t)b * PROJ + c];
    v[i] = 0.5f * (a + zv);
    ss += v[i] * v[i];
  }
#pragma unroll
  for (int off = 32; off; off >>= 1) ss += __shfl_down(ss, off);
  __shared__ float ps[4];
  if ((tid & 63) == 0) ps[tid >> 6] = ss;
  __syncthreads();
  float tot = ps[0] + ps[1] + ps[2] + ps[3];
  float nrm = rsqrtf(fmaxf(tot, 1e-12f));
  out[(size_t)b * 512 + tid] = v[0] * nrm;
  out[(size_t)b * 512 + tid + 256] = v[1] * nrm;
}

extern "C" void kernel_launch(void* const* d_in, const int* in_sizes, int n_in,
                              void* d_out, int out_size, void* d_ws, size_t ws_size,
                              hipStream_t stream) {
  (void)in_sizes; (void)n_in; (void)out_size; (void)ws_size;
  const float* X = (const float*)d_in[0];
  const float* Wk[2][3]; const float* Bi[2][3]; const float* Wp[2][3];
  for (int d = 0; d < 2; ++d)
    for (int l = 0; l < 3; ++l) {
      int base = 1 + d * 9 + l * 3;
      Wk[d][l] = (const float*)d_in[base];
      Bi[d][l] = (const float*)d_in[base + 1];
      Wp[d][l] = (const float*)d_in[base + 2];
    }

  char* ws = (char*)d_ws;
  size_t off = 0;
  auto alloc = [&](size_t bytes) -> void* {
    void* p = ws + off;
    off += (bytes + 255) & ~(size_t)255;
    return p;
  };

  const size_t SL = (size_t)NB * PROJ;    // halves per time-slot

  _Float16* X16 = (_Float16*)alloc((size_t)T_STEPS * NB * 64 * 2);
  _Float16* WkT[2][3];
  for (int d = 0; d < 2; ++d)
    for (int l = 0; l < 3; ++l)
      WkT[d][l] = (_Float16*)alloc((size_t)NGATE * (l == 0 ? 320 : 512) * 2);
  _Float16* WpT[2][3];
  for (int d = 0; d < 2; ++d)
    for (int l = 0; l < 3; ++l)
      WpT[d][l] = (_Float16*)alloc((size_t)PROJ * HID * 2);
  _Float16* Hbuf = (_Float16*)alloc(6UL * 4 * SL * 2);      // [l*2+d][4 slots][640][256]
  float* cst = (float*)alloc(6UL * NB * HID * 4);
  _Float16* gbuf = (_Float16*)alloc(6UL * NB * HID * 2);
  _Float16* embed = (_Float16*)alloc(4UL * SL * 2);         // [d][which][640][256]

  auto Hslot = [&](int l, int d, int slot) -> _Float16* {
    return Hbuf + (((size_t)(l * 2 + d) * 4) + slot) * SL;
  };

  // ---- prep ----
  {
    size_t tot = (size_t)T_STEPS * NB * 64;
    convX<<<dim3((unsigned)((tot + 255) / 256)), 256, 0, stream>>>(X, X16, tot);
  }
  for (int d = 0; d < 2; ++d)
    for (int l = 0; l < 3; ++l) {
      int Kpad = (l == 0) ? 320 : 512;
      size_t tot = (size_t)NGATE * Kpad;
      conv_wk<<<dim3((unsigned)((tot + 255) / 256)), 256, 0, stream>>>(
          Wk[d][l], WkT[d][l], (l == 0) ? 0 : 1, Kpad, tot);
      size_t totp = (size_t)PROJ * HID;
      conv_wp<<<dim3((unsigned)((totp + 255) / 256)), 256, 0, stream>>>(Wp[d][l], WpT[d][l], totp);
    }
  hipMemsetAsync(Hbuf, 0, 6UL * 4 * SL * 2, stream);        // zero rings (incl. h-init slots)
  hipMemsetAsync(cst, 0, 6UL * NB * HID * 4, stream);       // zero c state

  // ---- pipelined super-steps ----
  for (int s = 0; s <= 161; ++s) {
    GateArgs ga{};
    ProjArgs pa{};
    for (int l = 0; l < 3; ++l)
      for (int d = 0; d < 2; ++d) {
        int z = l * 2 + d;
        int t = s - l;                        // progress of layer l
        if (t < 0 || t > 159) { ga.act[z] = 0; pa.act[z] = 0; continue; }
        int tt = (d == 0) ? t : 159 - t;      // actual time index
        ga.act[z] = 1; pa.act[z] = 1;
        if (l == 0) {
          ga.A0[z] = X16 + (size_t)tt * NB * 64;
          ga.w0[z] = 64; ga.lda0[z] = 64; ga.K[z] = 320;
        } else {
          ga.A0[z] = Hslot(l - 1, d, (tt + 1) & 3);   // prev-layer output at time tt
          ga.w0[z] = 256; ga.lda0[z] = 256; ga.K[z] = 512;
        }
        int rdslot = (d == 0) ? (tt & 3) : ((tt + 2) & 3);
        ga.A1[z] = Hslot(l, d, rdslot);
        ga.Bw[z] = WkT[d][l];
        ga.bias[z] = Bi[d][l];
        ga.cst[z] = cst + (size_t)z * NB * HID;
        ga.g[z] = gbuf + (size_t)z * NB * HID;

        pa.G[z] = gbuf + (size_t)z * NB * HID;
        pa.Wp[z] = WpT[d][l];
        pa.out[z] = Hslot(l, d, (tt + 1) & 3);
        pa.out2[z] = nullptr;
        if (l == 2 && (tt == 0 || tt == 159))
          pa.out2[z] = embed + ((size_t)d * 2 + (tt == 0 ? 0 : 1)) * SL;
      }
    gate_step<<<dim3(24, 5, 6), 256, 0, stream>>>(ga);
    proj_step<<<dim3(4, 10, 6), 256, 0, stream>>>(pa);
  }

  readout<<<dim3(NB), 256, 0, stream>>>(embed, (float*)d_out);
}

// Round 4
// 7263.953 us; speedup vs baseline: 1.1432x; 1.1432x over previous
//
#include <hip/hip_runtime.h>

// BI-LSTM (TF LSTMCell w/ projection), T=160 B=640 F=40 HID=768 PROJ=256, 3 layers x 2 dirs.
// R4: gate kernel = R3's fragment-order DMA staging + R2's occupancy.
//  - 128x128 tile, 8 waves (512 thr), wave quadrant 32x64 (acc 2x4): 12 ds_read_b128 per
//    16 MFMAs (vs R2's 11 LDS ops per 8 MFMAs) -> ~1.5x higher LDS-pipe ceiling.
//  - global_load_lds width=16 into fragment-order 16x32 microtiles (1KB, exact MFMA lane
//    order): wave-uniform LDS base, conflict-free lane*16 frag reads, no ds_write traffic.
//  - 32.5KB LDS (A 16K | B 16K, epilogue overlays zs[128][65] f32) -> 3-4 blocks/CU,
//    24-32 waves/CU of cross-block TLP to hide the per-iter DMA drain (R3 failure mode).
// Pipeline structure unchanged (layer-wavefront, 6 z-slices/launch). Proj unchanged.

typedef _Float16 h8 __attribute__((ext_vector_type(8)));
typedef float f4 __attribute__((ext_vector_type(4)));

#define T_STEPS 160
#define NB 640
#define HID 768
#define PROJ 256
#define NGATE 3072           // 4*HID

__device__ __forceinline__ float sigm(float x) { return 1.0f / (1.0f + __expf(-x)); }
__device__ __forceinline__ float tanh_fast(float x) { return 2.0f / (1.0f + __expf(-2.0f * x)) - 1.0f; }

typedef __attribute__((address_space(1))) const void gas_t;
typedef __attribute__((address_space(3))) void las_t;
__device__ __forceinline__ void dma16(void* lds, const void* g) {
  // async global->LDS DMA, 16B/lane; LDS dest = wave-uniform base + lane*16 (HW-added)
  __builtin_amdgcn_global_load_lds((gas_t*)g, (las_t*)lds, 16, 0, 0);
}

struct GateArgs {
  const _Float16* A0[6];   // x-part source (X16 for l=0, prev-layer ring slot otherwise)
  const _Float16* A1[6];   // own h ring slot (h_{t-1} fw / h_{t+1} bw)
  const _Float16* Bw[6];   // WkT, gate-interleaved [3072][Kpad]
  const float*    bias[6];
  float*          cst[6];
  _Float16*       g[6];
  int w0[6];
  int lda0[6];
  int K[6];
  int act[6];
};

struct ProjArgs {
  const _Float16* G[6];    // [640][768] fp16
  const _Float16* Wp[6];   // [256][768] fp16 (B^T)
  _Float16* out[6];        // own ring write slot
  _Float16* out2[6];       // optional embed capture (layer 2, t in {0,159})
  int act[6];
};

// ---------------- gate GEMM: z = [x,h] @ WkT^T, fused bias+gates+c-update -> g ----------------
__global__ __launch_bounds__(512) void gate_step(GateArgs args) {
  const int z = blockIdx.z;
  if (!args.act[z]) return;

  __shared__ __align__(16) char sm[33280];   // A 16KB | B 16KB, overlaid by zs[128][65] f32
  char* smA = sm;                            // 16 microtiles (rg 0..7 x kk 0..1), 1KB each
  char* smB = sm + 16384;
  float (*zs)[65] = (float(*)[65])sm;

  const _Float16* A0 = args.A0[z];
  const _Float16* A1 = args.A1[z];
  const _Float16* Bw = args.Bw[z];
  const int w0 = args.w0[z], lda0 = args.lda0[z], K = args.K[z];
  const int n0 = blockIdx.x * 128;
  const int m0 = blockIdx.y * 128;
  const int tid = threadIdx.x;
  const int lane = tid & 63;
  const int wv = tid >> 6;         // 0..7
  const int wm = (wv & 3) * 32;    // wave covers rows [wm, wm+32), cols [wn, wn+64)
  const int wn = (wv >> 2) * 64;

  f4 acc[2][4] = {};

  // staging lane roles: row-in-microtile = lane&15, k-colgroup = (lane>>4)*8 halves
  const int mrow = lane & 15;
  const int kcol = (lane >> 4) * 8;

  for (int k0 = 0; k0 < K; k0 += 64) {
    const _Float16* Asrc; int Alda, kof;    // w0 is a multiple of 64 -> uniform per iter
    if (k0 < w0) { Asrc = A0; Alda = lda0; kof = k0; }
    else         { Asrc = A1; Alda = 256;  kof = k0 - w0; }
    __syncthreads();                        // prior iter's frag reads complete
    {
      // wave wv stages A rowgroup wv (kk=0,1) and B rowgroup wv (kk=0,1): 4 DMAs
      const _Float16* aput = Asrc + (size_t)(m0 + wv * 16 + mrow) * Alda + kof + kcol;
      dma16(smA + (wv * 2 + 0) * 1024, aput);
      dma16(smA + (wv * 2 + 1) * 1024, aput + 32);
      const _Float16* bput = Bw + (size_t)(n0 + wv * 16 + mrow) * K + k0 + kcol;
      dma16(smB + (wv * 2 + 0) * 1024, bput);
      dma16(smB + (wv * 2 + 1) * 1024, bput + 32);
    }
    __syncthreads();                        // drains vmcnt (DMA complete) per barrier semantics
#pragma unroll
    for (int kk = 0; kk < 2; ++kk) {
      h8 af[2], bf[4];
#pragma unroll
      for (int i = 0; i < 2; ++i)
        af[i] = *(const h8*)(smA + ((((wm >> 4) + i) * 2) + kk) * 1024 + lane * 16);
#pragma unroll
      for (int j = 0; j < 4; ++j)
        bf[j] = *(const h8*)(smB + ((((wn >> 4) + j) * 2) + kk) * 1024 + lane * 16);
#pragma unroll
      for (int i = 0; i < 2; ++i)
#pragma unroll
        for (int j = 0; j < 4; ++j)
          acc[i][j] = __builtin_amdgcn_mfma_f32_16x16x32_f16(af[i], bf[j], acc[i][j], 0, 0, 0);
    }
  }

  // epilogue: two 64-col passes through zs (16 units each)
  const float* bias = args.bias[z];
  float* cstate = args.cst[z];
  _Float16* gout = args.g[z];
#pragma unroll
  for (int p = 0; p < 2; ++p) {
    __syncthreads();
    if ((wv >> 2) == p) {                   // waves owning n-half p write their acc
#pragma unroll
      for (int mi = 0; mi < 2; ++mi)
#pragma unroll
        for (int ni = 0; ni < 4; ++ni)
#pragma unroll
          for (int r = 0; r < 4; ++r) {
            int row = wm + mi * 16 + ((lane >> 4) << 2) + r;  // C/D: row=(lane>>4)*4+reg
            int col = ni * 16 + (lane & 15);                  //      col=lane&15 (0..63)
            zs[row][col] = acc[mi][ni][r];
          }
    }
    __syncthreads();
    const int u0 = (n0 + p * 64) >> 2;      // first hidden unit of this pass
#pragma unroll
    for (int it = 0; it < 4; ++it) {
      int item = it * 512 + tid;            // 128 rows x 16 units
      int row = item >> 4;
      int u = item & 15;
      float zi = zs[row][4 * u + 0] + bias[0 * HID + u0 + u];
      float zj = zs[row][4 * u + 1] + bias[1 * HID + u0 + u];
      float zf = zs[row][4 * u + 2] + bias[2 * HID + u0 + u];
      float zo = zs[row][4 * u + 3] + bias[3 * HID + u0 + u];
      size_t co = (size_t)(m0 + row) * HID + u0 + u;
      float cold = cstate[co];
      float cnew = sigm(zf + 1.0f) * cold + sigm(zi) * tanh_fast(zj);  // forget_bias=1.0
      float g = sigm(zo) * tanh_fast(cnew);
      cstate[co] = cnew;
      gout[co] = (_Float16)g;
    }
  }
}

// ---------------- projection GEMM: h = g @ WpT^T ----------------
// 64x64 tile, 256 threads, K=768. (unchanged from R2 - known good)
__global__ __launch_bounds__(256) void proj_step(ProjArgs args) {
  const int z = blockIdx.z;
  if (!args.act[z]) return;

  __shared__ __align__(16) _Float16 As[64][72];
  __shared__ __align__(16) _Float16 Bs[64][72];

  const _Float16* A = args.G[z];
  const _Float16* B = args.Wp[z];
  const int n0 = blockIdx.x * 64;
  const int m0 = blockIdx.y * 64;
  const int tid = threadIdx.x;
  const int lane = tid & 63;
  const int wv = tid >> 6;
  const int wm = (wv & 1) * 32;
  const int wn = (wv >> 1) * 32;

  f4 acc[2][2] = {};
  const int lr = tid >> 3;
  const int lkg = (tid & 7) * 8;

  for (int k0 = 0; k0 < HID; k0 += 64) {
    const int gk = k0 + lkg;
    h8 av0 = *(const h8*)(A + (size_t)(m0 + lr) * HID + gk);
    h8 av1 = *(const h8*)(A + (size_t)(m0 + lr + 32) * HID + gk);
    h8 bv0 = *(const h8*)(B + (size_t)(n0 + lr) * HID + gk);
    h8 bv1 = *(const h8*)(B + (size_t)(n0 + lr + 32) * HID + gk);
    __syncthreads();
    *(h8*)&As[lr][lkg] = av0;
    *(h8*)&As[lr + 32][lkg] = av1;
    *(h8*)&Bs[lr][lkg] = bv0;
    *(h8*)&Bs[lr + 32][lkg] = bv1;
    __syncthreads();
    const int mr = wm + (lane & 15);
    const int nr = wn + (lane & 15);
#pragma unroll
    for (int kk = 0; kk < 2; ++kk) {
      const int kq = ((lane >> 4) * 8) + kk * 32;
      h8 a0 = *(const h8*)&As[mr][kq];
      h8 a1 = *(const h8*)&As[mr + 16][kq];
      h8 b0 = *(const h8*)&Bs[nr][kq];
      h8 b1 = *(const h8*)&Bs[nr + 16][kq];
      acc[0][0] = __builtin_amdgcn_mfma_f32_16x16x32_f16(a0, b0, acc[0][0], 0, 0, 0);
      acc[0][1] = __builtin_amdgcn_mfma_f32_16x16x32_f16(a0, b1, acc[0][1], 0, 0, 0);
      acc[1][0] = __builtin_amdgcn_mfma_f32_16x16x32_f16(a1, b0, acc[1][0], 0, 0, 0);
      acc[1][1] = __builtin_amdgcn_mfma_f32_16x16x32_f16(a1, b1, acc[1][1], 0, 0, 0);
    }
  }

  _Float16* outp = args.out[z];
  _Float16* out2 = args.out2[z];
#pragma unroll
  for (int mi = 0; mi < 2; ++mi)
#pragma unroll
    for (int ni = 0; ni < 2; ++ni)
#pragma unroll
      for (int r = 0; r < 4; ++r) {
        int row = wm + mi * 16 + ((lane >> 4) << 2) + r;
        int col = wn + ni * 16 + (lane & 15);
        _Float16 v = (_Float16)acc[mi][ni][r];
        size_t o = (size_t)(m0 + row) * PROJ + (n0 + col);
        outp[o] = v;
        if (out2) out2[o] = v;
      }
}

// ---------------- prep kernels ----------------
__global__ void convX(const float* __restrict__ X, _Float16* __restrict__ X16, size_t total) {
  size_t i = (size_t)blockIdx.x * 256 + threadIdx.x;
  if (i >= total) return;
  int p = (int)(i & 63);
  size_t tb = i >> 6;
  float v = (p < 40) ? X[tb * 40 + p] : 0.0f;
  X16[i] = (_Float16)v;
}

// Wk fp32 [Kin+256, 3072] -> WkT fp16 [3072][Kpad], gate-interleaved rows n'=4u+g,
// layer0 k-map: k<40 -> Wk[k]; 40..63 -> 0; 64..319 -> Wk[k-24]
__global__ void conv_wk(const float* __restrict__ Wk, _Float16* __restrict__ out,
                        int mode, int Kpad, size_t total) {
  size_t i = (size_t)blockIdx.x * 256 + threadIdx.x;
  if (i >= total) return;
  int k = (int)(i % Kpad);
  int n = (int)(i / Kpad);
  int u = n >> 2, g = n & 3;
  int col = g * HID + u;
  float v;
  if (mode == 0) {
    if (k < 40)      v = Wk[(size_t)k * NGATE + col];
    else if (k < 64) v = 0.0f;
    else             v = Wk[(size_t)(k - 24) * NGATE + col];
  } else {
    v = Wk[(size_t)k * NGATE + col];
  }
  out[i] = (_Float16)v;
}

__global__ void conv_wp(const float* __restrict__ Wp, _Float16* __restrict__ out, size_t total) {
  size_t i = (size_t)blockIdx.x * 256 + threadIdx.x;
  if (i >= total) return;
  int k = (int)(i % HID);
  int c = (int)(i / HID);
  out[i] = (_Float16)Wp[(size_t)k * PROJ + c];
}

// ---------------- readout ----------------
__global__ __launch_bounds__(256) void readout(const _Float16* __restrict__ E, float* __restrict__ out) {
  const size_t SL = (size_t)NB * PROJ;
  int b = blockIdx.x, tid = threadIdx.x;
  float v[2];
  float ss = 0.0f;
#pragma unroll
  for (int i = 0; i < 2; ++i) {
    int j = tid + i * 256;
    int d = j >> 8, c = j & 255;
    const _Float16* base = E + (size_t)d * 2 * SL;
    float a = (float)base[(size_t)b * PROJ + c];
    float zv = (float)base[SL + (size_t)b * PROJ + c];
    v[i] = 0.5f * (a + zv);
    ss += v[i] * v[i];
  }
#pragma unroll
  for (int off = 32; off; off >>= 1) ss += __shfl_down(ss, off);
  __shared__ float ps[4];
  if ((tid & 63) == 0) ps[tid >> 6] = ss;
  __syncthreads();
  float tot = ps[0] + ps[1] + ps[2] + ps[3];
  float nrm = rsqrtf(fmaxf(tot, 1e-12f));
  out[(size_t)b * 512 + tid] = v[0] * nrm;
  out[(size_t)b * 512 + tid + 256] = v[1] * nrm;
}

extern "C" void kernel_launch(void* const* d_in, const int* in_sizes, int n_in,
                              void* d_out, int out_size, void* d_ws, size_t ws_size,
                              hipStream_t stream) {
  (void)in_sizes; (void)n_in; (void)out_size; (void)ws_size;
  const float* X = (const float*)d_in[0];
  const float* Wk[2][3]; const float* Bi[2][3]; const float* Wp[2][3];
  for (int d = 0; d < 2; ++d)
    for (int l = 0; l < 3; ++l) {
      int base = 1 + d * 9 + l * 3;
      Wk[d][l] = (const float*)d_in[base];
      Bi[d][l] = (const float*)d_in[base + 1];
      Wp[d][l] = (const float*)d_in[base + 2];
    }

  char* ws = (char*)d_ws;
  size_t off = 0;
  auto alloc = [&](size_t bytes) -> void* {
    void* p = ws + off;
    off += (bytes + 255) & ~(size_t)255;
    return p;
  };

  const size_t SL = (size_t)NB * PROJ;    // halves per time-slot

  _Float16* X16 = (_Float16*)alloc((size_t)T_STEPS * NB * 64 * 2);
  _Float16* WkT[2][3];
  for (int d = 0; d < 2; ++d)
    for (int l = 0; l < 3; ++l)
      WkT[d][l] = (_Float16*)alloc((size_t)NGATE * (l == 0 ? 320 : 512) * 2);
  _Float16* WpT[2][3];
  for (int d = 0; d < 2; ++d)
    for (int l = 0; l < 3; ++l)
      WpT[d][l] = (_Float16*)alloc((size_t)PROJ * HID * 2);
  _Float16* Hbuf = (_Float16*)alloc(6UL * 4 * SL * 2);      // [l*2+d][4 slots][640][256]
  float* cst = (float*)alloc(6UL * NB * HID * 4);
  _Float16* gbuf = (_Float16*)alloc(6UL * NB * HID * 2);
  _Float16* embed = (_Float16*)alloc(4UL * SL * 2);         // [d][which][640][256]

  auto Hslot = [&](int l, int d, int slot) -> _Float16* {
    return Hbuf + (((size_t)(l * 2 + d) * 4) + slot) * SL;
  };

  // ---- prep ----
  {
    size_t tot = (size_t)T_STEPS * NB * 64;
    convX<<<dim3((unsigned)((tot + 255) / 256)), 256, 0, stream>>>(X, X16, tot);
  }
  for (int d = 0; d < 2; ++d)
    for (int l = 0; l < 3; ++l) {
      int Kpad = (l == 0) ? 320 : 512;
      size_t tot = (size_t)NGATE * Kpad;
      conv_wk<<<dim3((unsigned)((tot + 255) / 256)), 256, 0, stream>>>(
          Wk[d][l], WkT[d][l], (l == 0) ? 0 : 1, Kpad, tot);
      size_t totp = (size_t)PROJ * HID;
      conv_wp<<<dim3((unsigned)((totp + 255) / 256)), 256, 0, stream>>>(Wp[d][l], WpT[d][l], totp);
    }
  hipMemsetAsync(Hbuf, 0, 6UL * 4 * SL * 2, stream);        // zero rings (incl. h-init slots)
  hipMemsetAsync(cst, 0, 6UL * NB * HID * 4, stream);       // zero c state

  // ---- pipelined super-steps ----
  for (int s = 0; s <= 161; ++s) {
    GateArgs ga{};
    ProjArgs pa{};
    for (int l = 0; l < 3; ++l)
      for (int d = 0; d < 2; ++d) {
        int z = l * 2 + d;
        int t = s - l;                        // progress of layer l
        if (t < 0 || t > 159) { ga.act[z] = 0; pa.act[z] = 0; continue; }
        int tt = (d == 0) ? t : 159 - t;      // actual time index
        ga.act[z] = 1; pa.act[z] = 1;
        if (l == 0) {
          ga.A0[z] = X16 + (size_t)tt * NB * 64;
          ga.w0[z] = 64; ga.lda0[z] = 64; ga.K[z] = 320;
        } else {
          ga.A0[z] = Hslot(l - 1, d, (tt + 1) & 3);   // prev-layer output at time tt
          ga.w0[z] = 256; ga.lda0[z] = 256; ga.K[z] = 512;
        }
        int rdslot = (d == 0) ? (tt & 3) : ((tt + 2) & 3);
        ga.A1[z] = Hslot(l, d, rdslot);
        ga.Bw[z] = WkT[d][l];
        ga.bias[z] = Bi[d][l];
        ga.cst[z] = cst + (size_t)z * NB * HID;
        ga.g[z] = gbuf + (size_t)z * NB * HID;

        pa.G[z] = gbuf + (size_t)z * NB * HID;
        pa.Wp[z] = WpT[d][l];
        pa.out[z] = Hslot(l, d, (tt + 1) & 3);
        pa.out2[z] = nullptr;
        if (l == 2 && (tt == 0 || tt == 159))
          pa.out2[z] = embed + ((size_t)d * 2 + (tt == 0 ? 0 : 1)) * SL;
      }
    gate_step<<<dim3(24, 5, 6), 512, 0, stream>>>(ga);
    proj_step<<<dim3(4, 10, 6), 256, 0, stream>>>(pa);
  }

  readout<<<dim3(NB), 256, 0, stream>>>(embed, (float*)d_out);
}

// Round 5
// 6106.815 us; speedup vs baseline: 1.3598x; 1.1895x over previous
//
#include <hip/hip_runtime.h>

// BI-LSTM (TF LSTMCell w/ projection), T=160 B=640 F=40 HID=768 PROJ=256, 3 layers x 2 dirs.
// R5: gate kernel = R2's VGPR->ds_write staging (compiler software-pipelines the global
// loads across K-iters -- the thing R3/R4's global_load_lds structurally cannot do at K=512)
// + R4's 32x64 wave quadrants (acc 2x4: 12 ds_read per 16 MFMA) + 128x128 tile so the grid
// is 720 blocks = ONE scheduling round at 4 blocks/CU (R2's 1440 = 1.4 rounds, ~30% tail).
// LDS: As[128][72] + Bs[128][72] = 36.9KB, epilogue overlays zs[128][65] f32.

typedef _Float16 h8 __attribute__((ext_vector_type(8)));
typedef float f4 __attribute__((ext_vector_type(4)));

#define T_STEPS 160
#define NB 640
#define HID 768
#define PROJ 256
#define NGATE 3072           // 4*HID

__device__ __forceinline__ float sigm(float x) { return 1.0f / (1.0f + __expf(-x)); }
__device__ __forceinline__ float tanh_fast(float x) { return 2.0f / (1.0f + __expf(-2.0f * x)) - 1.0f; }

struct GateArgs {
  const _Float16* A0[6];   // x-part source (X16 for l=0, prev-layer ring slot otherwise)
  const _Float16* A1[6];   // own h ring slot (h_{t-1} fw / h_{t+1} bw)
  const _Float16* Bw[6];   // WkT, gate-interleaved [3072][Kpad]
  const float*    bias[6];
  float*          cst[6];
  _Float16*       g[6];
  int w0[6];
  int lda0[6];
  int K[6];
  int act[6];
};

struct ProjArgs {
  const _Float16* G[6];    // [640][768] fp16
  const _Float16* Wp[6];   // [256][768] fp16 (B^T)
  _Float16* out[6];        // own ring write slot
  _Float16* out2[6];       // optional embed capture (layer 2, t in {0,159})
  int act[6];
};

// ---------------- gate GEMM: z = [x,h] @ WkT^T, fused bias+gates+c-update -> g ----------------
__global__ __launch_bounds__(512) void gate_step(GateArgs args) {
  const int z = blockIdx.z;
  if (!args.act[z]) return;

  __shared__ __align__(16) char sm[36864];       // As 18KB | Bs 18KB; epilogue overlays zs
  _Float16 (*As)[72] = (_Float16(*)[72])sm;      // [128][72]
  _Float16 (*Bs)[72] = (_Float16(*)[72])(sm + 18432);
  float (*zs)[65] = (float(*)[65])sm;            // [128][65] f32 = 33.3KB

  const _Float16* A0 = args.A0[z];
  const _Float16* A1 = args.A1[z];
  const _Float16* Bw = args.Bw[z];
  const int w0 = args.w0[z], lda0 = args.lda0[z], K = args.K[z];
  const int n0 = blockIdx.x * 128;
  const int m0 = blockIdx.y * 128;
  const int tid = threadIdx.x;
  const int lane = tid & 63;
  const int wv = tid >> 6;         // 0..7
  const int wm = (wv & 3) * 32;    // wave covers rows [wm, wm+32), cols [wn, wn+64)
  const int wn = (wv >> 2) * 64;

  f4 acc[2][4] = {};

  const int lr = tid >> 3;          // 0..63 (handles rows lr and lr+64)
  const int lkg = (tid & 7) * 8;    // k-group 0,8,..,56

  for (int k0 = 0; k0 < K; k0 += 64) {
    const int gk = k0 + lkg;
    // global loads FIRST (VGPR staging) -- compiler hoists these across the barrier,
    // overlapping their latency with the previous iteration's MFMAs.
    h8 av0, av1;
    if (gk < w0) {
      av0 = *(const h8*)(A0 + (size_t)(m0 + lr) * lda0 + gk);
      av1 = *(const h8*)(A0 + (size_t)(m0 + lr + 64) * lda0 + gk);
    } else {
      av0 = *(const h8*)(A1 + (size_t)(m0 + lr) * 256 + (gk - w0));
      av1 = *(const h8*)(A1 + (size_t)(m0 + lr + 64) * 256 + (gk - w0));
    }
    h8 bv0 = *(const h8*)(Bw + (size_t)(n0 + lr) * K + gk);
    h8 bv1 = *(const h8*)(Bw + (size_t)(n0 + lr + 64) * K + gk);
    __syncthreads();                 // prior iter's frag reads complete
    *(h8*)&As[lr][lkg] = av0;
    *(h8*)&As[lr + 64][lkg] = av1;
    *(h8*)&Bs[lr][lkg] = bv0;
    *(h8*)&Bs[lr + 64][lkg] = bv1;
    __syncthreads();
#pragma unroll
    for (int kk = 0; kk < 2; ++kk) {
      const int kq = ((lane >> 4) * 8) + kk * 32;
      h8 af[2], bf[4];
#pragma unroll
      for (int i = 0; i < 2; ++i)
        af[i] = *(const h8*)&As[wm + (lane & 15) + 16 * i][kq];
#pragma unroll
      for (int j = 0; j < 4; ++j)
        bf[j] = *(const h8*)&Bs[wn + (lane & 15) + 16 * j][kq];
#pragma unroll
      for (int i = 0; i < 2; ++i)
#pragma unroll
        for (int j = 0; j < 4; ++j)
          acc[i][j] = __builtin_amdgcn_mfma_f32_16x16x32_f16(af[i], bf[j], acc[i][j], 0, 0, 0);
    }
  }

  // epilogue: two 64-col passes through zs (16 hidden units each)
  const float* bias = args.bias[z];
  float* cstate = args.cst[z];
  _Float16* gout = args.g[z];
#pragma unroll
  for (int p = 0; p < 2; ++p) {
    __syncthreads();
    if ((wv >> 2) == p) {                   // waves owning n-half p write their acc
#pragma unroll
      for (int mi = 0; mi < 2; ++mi)
#pragma unroll
        for (int ni = 0; ni < 4; ++ni)
#pragma unroll
          for (int r = 0; r < 4; ++r) {
            int row = wm + mi * 16 + ((lane >> 4) << 2) + r;  // C/D: row=(lane>>4)*4+reg
            int col = ni * 16 + (lane & 15);                  //      col=lane&15 (0..63)
            zs[row][col] = acc[mi][ni][r];
          }
    }
    __syncthreads();
    const int u0 = (n0 + p * 64) >> 2;      // first hidden unit of this pass
#pragma unroll
    for (int it = 0; it < 4; ++it) {
      int item = it * 512 + tid;            // 128 rows x 16 units
      int row = item >> 4;
      int u = item & 15;
      float zi = zs[row][4 * u + 0] + bias[0 * HID + u0 + u];
      float zj = zs[row][4 * u + 1] + bias[1 * HID + u0 + u];
      float zf = zs[row][4 * u + 2] + bias[2 * HID + u0 + u];
      float zo = zs[row][4 * u + 3] + bias[3 * HID + u0 + u];
      size_t co = (size_t)(m0 + row) * HID + u0 + u;
      float cold = cstate[co];
      float cnew = sigm(zf + 1.0f) * cold + sigm(zi) * tanh_fast(zj);  // forget_bias=1.0
      float g = sigm(zo) * tanh_fast(cnew);
      cstate[co] = cnew;
      gout[co] = (_Float16)g;
    }
  }
}

// ---------------- projection GEMM: h = g @ WpT^T ----------------
// 64x64 tile, 256 threads, K=768. (unchanged - known good)
__global__ __launch_bounds__(256) void proj_step(ProjArgs args) {
  const int z = blockIdx.z;
  if (!args.act[z]) return;

  __shared__ __align__(16) _Float16 As[64][72];
  __shared__ __align__(16) _Float16 Bs[64][72];

  const _Float16* A = args.G[z];
  const _Float16* B = args.Wp[z];
  const int n0 = blockIdx.x * 64;
  const int m0 = blockIdx.y * 64;
  const int tid = threadIdx.x;
  const int lane = tid & 63;
  const int wv = tid >> 6;
  const int wm = (wv & 1) * 32;
  const int wn = (wv >> 1) * 32;

  f4 acc[2][2] = {};
  const int lr = tid >> 3;
  const int lkg = (tid & 7) * 8;

  for (int k0 = 0; k0 < HID; k0 += 64) {
    const int gk = k0 + lkg;
    h8 av0 = *(const h8*)(A + (size_t)(m0 + lr) * HID + gk);
    h8 av1 = *(const h8*)(A + (size_t)(m0 + lr + 32) * HID + gk);
    h8 bv0 = *(const h8*)(B + (size_t)(n0 + lr) * HID + gk);
    h8 bv1 = *(const h8*)(B + (size_t)(n0 + lr + 32) * HID + gk);
    __syncthreads();
    *(h8*)&As[lr][lkg] = av0;
    *(h8*)&As[lr + 32][lkg] = av1;
    *(h8*)&Bs[lr][lkg] = bv0;
    *(h8*)&Bs[lr + 32][lkg] = bv1;
    __syncthreads();
    const int mr = wm + (lane & 15);
    const int nr = wn + (lane & 15);
#pragma unroll
    for (int kk = 0; kk < 2; ++kk) {
      const int kq = ((lane >> 4) * 8) + kk * 32;
      h8 a0 = *(const h8*)&As[mr][kq];
      h8 a1 = *(const h8*)&As[mr + 16][kq];
      h8 b0 = *(const h8*)&Bs[nr][kq];
      h8 b1 = *(const h8*)&Bs[nr + 16][kq];
      acc[0][0] = __builtin_amdgcn_mfma_f32_16x16x32_f16(a0, b0, acc[0][0], 0, 0, 0);
      acc[0][1] = __builtin_amdgcn_mfma_f32_16x16x32_f16(a0, b1, acc[0][1], 0, 0, 0);
      acc[1][0] = __builtin_amdgcn_mfma_f32_16x16x32_f16(a1, b0, acc[1][0], 0, 0, 0);
      acc[1][1] = __builtin_amdgcn_mfma_f32_16x16x32_f16(a1, b1, acc[1][1], 0, 0, 0);
    }
  }

  _Float16* outp = args.out[z];
  _Float16* out2 = args.out2[z];
#pragma unroll
  for (int mi = 0; mi < 2; ++mi)
#pragma unroll
    for (int ni = 0; ni < 2; ++ni)
#pragma unroll
      for (int r = 0; r < 4; ++r) {
        int row = wm + mi * 16 + ((lane >> 4) << 2) + r;
        int col = wn + ni * 16 + (lane & 15);
        _Float16 v = (_Float16)acc[mi][ni][r];
        size_t o = (size_t)(m0 + row) * PROJ + (n0 + col);
        outp[o] = v;
        if (out2) out2[o] = v;
      }
}

// ---------------- prep kernels ----------------
__global__ void convX(const float* __restrict__ X, _Float16* __restrict__ X16, size_t total) {
  size_t i = (size_t)blockIdx.x * 256 + threadIdx.x;
  if (i >= total) return;
  int p = (int)(i & 63);
  size_t tb = i >> 6;
  float v = (p < 40) ? X[tb * 40 + p] : 0.0f;
  X16[i] = (_Float16)v;
}

// Wk fp32 [Kin+256, 3072] -> WkT fp16 [3072][Kpad], gate-interleaved rows n'=4u+g,
// layer0 k-map: k<40 -> Wk[k]; 40..63 -> 0; 64..319 -> Wk[k-24]
__global__ void conv_wk(const float* __restrict__ Wk, _Float16* __restrict__ out,
                        int mode, int Kpad, size_t total) {
  size_t i = (size_t)blockIdx.x * 256 + threadIdx.x;
  if (i >= total) return;
  int k = (int)(i % Kpad);
  int n = (int)(i / Kpad);
  int u = n >> 2, g = n & 3;
  int col = g * HID + u;
  float v;
  if (mode == 0) {
    if (k < 40)      v = Wk[(size_t)k * NGATE + col];
    else if (k < 64) v = 0.0f;
    else             v = Wk[(size_t)(k - 24) * NGATE + col];
  } else {
    v = Wk[(size_t)k * NGATE + col];
  }
  out[i] = (_Float16)v;
}

__global__ void conv_wp(const float* __restrict__ Wp, _Float16* __restrict__ out, size_t total) {
  size_t i = (size_t)blockIdx.x * 256 + threadIdx.x;
  if (i >= total) return;
  int k = (int)(i % HID);
  int c = (int)(i / HID);
  out[i] = (_Float16)Wp[(size_t)k * PROJ + c];
}

// ---------------- readout ----------------
__global__ __launch_bounds__(256) void readout(const _Float16* __restrict__ E, float* __restrict__ out) {
  const size_t SL = (size_t)NB * PROJ;
  int b = blockIdx.x, tid = threadIdx.x;
  float v[2];
  float ss = 0.0f;
#pragma unroll
  for (int i = 0; i < 2; ++i) {
    int j = tid + i * 256;
    int d = j >> 8, c = j & 255;
    const _Float16* base = E + (size_t)d * 2 * SL;
    float a = (float)base[(size_t)b * PROJ + c];
    float zv = (float)base[SL + (size_t)b * PROJ + c];
    v[i] = 0.5f * (a + zv);
    ss += v[i] * v[i];
  }
#pragma unroll
  for (int off = 32; off; off >>= 1) ss += __shfl_down(ss, off);
  __shared__ float ps[4];
  if ((tid & 63) == 0) ps[tid >> 6] = ss;
  __syncthreads();
  float tot = ps[0] + ps[1] + ps[2] + ps[3];
  float nrm = rsqrtf(fmaxf(tot, 1e-12f));
  out[(size_t)b * 512 + tid] = v[0] * nrm;
  out[(size_t)b * 512 + tid + 256] = v[1] * nrm;
}

extern "C" void kernel_launch(void* const* d_in, const int* in_sizes, int n_in,
                              void* d_out, int out_size, void* d_ws, size_t ws_size,
                              hipStream_t stream) {
  (void)in_sizes; (void)n_in; (void)out_size; (void)ws_size;
  const float* X = (const float*)d_in[0];
  const float* Wk[2][3]; const float* Bi[2][3]; const float* Wp[2][3];
  for (int d = 0; d < 2; ++d)
    for (int l = 0; l < 3; ++l) {
      int base = 1 + d * 9 + l * 3;
      Wk[d][l] = (const float*)d_in[base];
      Bi[d][l] = (const float*)d_in[base + 1];
      Wp[d][l] = (const float*)d_in[base + 2];
    }

  char* ws = (char*)d_ws;
  size_t off = 0;
  auto alloc = [&](size_t bytes) -> void* {
    void* p = ws + off;
    off += (bytes + 255) & ~(size_t)255;
    return p;
  };

  const size_t SL = (size_t)NB * PROJ;    // halves per time-slot

  _Float16* X16 = (_Float16*)alloc((size_t)T_STEPS * NB * 64 * 2);
  _Float16* WkT[2][3];
  for (int d = 0; d < 2; ++d)
    for (int l = 0; l < 3; ++l)
      WkT[d][l] = (_Float16*)alloc((size_t)NGATE * (l == 0 ? 320 : 512) * 2);
  _Float16* WpT[2][3];
  for (int d = 0; d < 2; ++d)
    for (int l = 0; l < 3; ++l)
      WpT[d][l] = (_Float16*)alloc((size_t)PROJ * HID * 2);
  _Float16* Hbuf = (_Float16*)alloc(6UL * 4 * SL * 2);      // [l*2+d][4 slots][640][256]
  float* cst = (float*)alloc(6UL * NB * HID * 4);
  _Float16* gbuf = (_Float16*)alloc(6UL * NB * HID * 2);
  _Float16* embed = (_Float16*)alloc(4UL * SL * 2);         // [d][which][640][256]

  auto Hslot = [&](int l, int d, int slot) -> _Float16* {
    return Hbuf + (((size_t)(l * 2 + d) * 4) + slot) * SL;
  };

  // ---- prep ----
  {
    size_t tot = (size_t)T_STEPS * NB * 64;
    convX<<<dim3((unsigned)((tot + 255) / 256)), 256, 0, stream>>>(X, X16, tot);
  }
  for (int d = 0; d < 2; ++d)
    for (int l = 0; l < 3; ++l) {
      int Kpad = (l == 0) ? 320 : 512;
      size_t tot = (size_t)NGATE * Kpad;
      conv_wk<<<dim3((unsigned)((tot + 255) / 256)), 256, 0, stream>>>(
          Wk[d][l], WkT[d][l], (l == 0) ? 0 : 1, Kpad, tot);
      size_t totp = (size_t)PROJ * HID;
      conv_wp<<<dim3((unsigned)((totp + 255) / 256)), 256, 0, stream>>>(Wp[d][l], WpT[d][l], totp);
    }
  hipMemsetAsync(Hbuf, 0, 6UL * 4 * SL * 2, stream);        // zero rings (incl. h-init slots)
  hipMemsetAsync(cst, 0, 6UL * NB * HID * 4, stream);       // zero c state

  // ---- pipelined super-steps ----
  for (int s = 0; s <= 161; ++s) {
    GateArgs ga{};
    ProjArgs pa{};
    for (int l = 0; l < 3; ++l)
      for (int d = 0; d < 2; ++d) {
        int z = l * 2 + d;
        int t = s - l;                        // progress of layer l
        if (t < 0 || t > 159) { ga.act[z] = 0; pa.act[z] = 0; continue; }
        int tt = (d == 0) ? t : 159 - t;      // actual time index
        ga.act[z] = 1; pa.act[z] = 1;
        if (l == 0) {
          ga.A0[z] = X16 + (size_t)tt * NB * 64;
          ga.w0[z] = 64; ga.lda0[z] = 64; ga.K[z] = 320;
        } else {
          ga.A0[z] = Hslot(l - 1, d, (tt + 1) & 3);   // prev-layer output at time tt
          ga.w0[z] = 256; ga.lda0[z] = 256; ga.K[z] = 512;
        }
        int rdslot = (d == 0) ? (tt & 3) : ((tt + 2) & 3);
        ga.A1[z] = Hslot(l, d, rdslot);
        ga.Bw[z] = WkT[d][l];
        ga.bias[z] = Bi[d][l];
        ga.cst[z] = cst + (size_t)z * NB * HID;
        ga.g[z] = gbuf + (size_t)z * NB * HID;

        pa.G[z] = gbuf + (size_t)z * NB * HID;
        pa.Wp[z] = WpT[d][l];
        pa.out[z] = Hslot(l, d, (tt + 1) & 3);
        pa.out2[z] = nullptr;
        if (l == 2 && (tt == 0 || tt == 159))
          pa.out2[z] = embed + ((size_t)d * 2 + (tt == 0 ? 0 : 1)) * SL;
      }
    gate_step<<<dim3(24, 5, 6), 512, 0, stream>>>(ga);
    proj_step<<<dim3(4, 10, 6), 256, 0, stream>>>(pa);
  }

  readout<<<dim3(NB), 256, 0, stream>>>(embed, (float*)d_out);
}